// Round 2
// baseline (123.494 us; speedup 1.0000x reference)
//
#include <hip/hip_runtime.h>
#include <cstdint>
#include <cstddef>

// Problem constants (fixed by the reference)
constexpr int Bc = 4, Tc = 4096, Ec = 1024, Hc = 16, Dc = 64, CHc = 64;
constexpr int NCH = Tc / CHc;         // 64 chunks per (b,h) sequence
constexpr int LP = 72;                // padded LDS row stride in bf16 elems (144B)

typedef __attribute__((ext_vector_type(8))) short short8;  // 8 bf16 MFMA A/B frag
typedef __attribute__((ext_vector_type(4))) float f32x4;   // MFMA C/D frag

__device__ __forceinline__ unsigned short f2bf(float f) {
  union { float f; unsigned int u; } v; v.f = f;
  return (unsigned short)((v.u + 0x7FFFu + ((v.u >> 16) & 1u)) >> 16);  // RNE
}
__device__ __forceinline__ float bf2f(unsigned short u) {
  union { unsigned int u; float f; } v; v.u = ((unsigned int)u) << 16;
  return v.f;
}
__device__ __forceinline__ float phi_elu1(float x) {   // elu(x)+1
  return x > 0.f ? x + 1.f : __expf(x);
}
__device__ __forceinline__ short8 ld8(const unsigned short* p) {
  return *reinterpret_cast<const short8*>(p);
}
__device__ __forceinline__ void st8(unsigned short* p, short8 v) {
  *reinterpret_cast<short8*>(p) = v;
}

#define MFMA_B16(a, b, c) __builtin_amdgcn_mfma_f32_16x16x32_bf16((a), (b), (c), 0, 0, 0)

// Stage one [64 tok x 64 d] fp32 x-chunk into bf16 LDS (row-major, LP stride).
__device__ __forceinline__ void stage_x(const float* __restrict__ xbase, int sr, int sc,
                                        unsigned short* __restrict__ s_x) {
  const float* xr = xbase + (size_t)sr * Ec + sc * 16;
  const float4* xf = reinterpret_cast<const float4*>(xr);
  float4 f0 = xf[0], f1 = xf[1], f2 = xf[2], f3 = xf[3];
  union { unsigned short us[16]; short8 v[2]; } pk;
  pk.us[0] = f2bf(f0.x);  pk.us[1] = f2bf(f0.y);  pk.us[2] = f2bf(f0.z);  pk.us[3] = f2bf(f0.w);
  pk.us[4] = f2bf(f1.x);  pk.us[5] = f2bf(f1.y);  pk.us[6] = f2bf(f1.z);  pk.us[7] = f2bf(f1.w);
  pk.us[8] = f2bf(f2.x);  pk.us[9] = f2bf(f2.y);  pk.us[10] = f2bf(f2.z); pk.us[11] = f2bf(f2.w);
  pk.us[12] = f2bf(f3.x); pk.us[13] = f2bf(f3.y); pk.us[14] = f2bf(f3.z); pk.us[15] = f2bf(f3.w);
  unsigned short* dst = s_x + sr * LP + sc * 16;
  st8(dst, pk.v[0]); st8(dst + 8, pk.v[1]);
}

// ---------------- pass0: W[d][e] fp32 -> WT[e][d] bf16 (q,k,v,o) ----------------
__global__ void prep_weights(const float* __restrict__ Wq, const float* __restrict__ Wk,
                             const float* __restrict__ Wv, const float* __restrict__ Wo,
                             unsigned short* __restrict__ wT) {
  int tid = blockIdx.x * blockDim.x + threadIdx.x;
  if (tid >= 4 * Dc * Dc) return;
  int m = tid >> 12, i = tid & 4095, d = i >> 6, e = i & 63;
  const float* W = (m == 0) ? Wq : (m == 1) ? Wk : (m == 2) ? Wv : Wo;
  wT[m * 4096 + e * 64 + d] = f2bf(W[d * 64 + e]);
}

// ---------------- pass1: per-chunk KV^T = sum_t v^T k  -> bf16 ws ----------------
// One block per (bh, chunk). Output kvc[bh*64+ch][d][e] = sum_t v[t][d]*phi(k)[t][e].
__global__ __launch_bounds__(256, 4) void pass1_kv(
    const float* __restrict__ x, const unsigned short* __restrict__ wT,
    unsigned short* __restrict__ kvc) {
  __shared__ unsigned short s_x[64 * LP];
  __shared__ unsigned short s_kT[64 * LP];
  __shared__ unsigned short s_vT[64 * LP];

  const int tid = threadIdx.x;
  const int w = tid >> 6, lane = tid & 63, lr = lane & 15, lq = lane >> 4;
  const int bh = blockIdx.x, ch = blockIdx.y;
  const int b = bh >> 4, h = bh & 15;
  const float* xbase = x + ((size_t)b * Tc + (size_t)ch * CHc) * Ec + h * Dc;
  const unsigned short* wkT = wT + 4096;
  const unsigned short* wvT = wT + 2 * 4096;
  const int sr = tid >> 2, sc = tid & 3;
  const f32x4 zero4 = {0.f, 0.f, 0.f, 0.f};

  stage_x(xbase, sr, sc, s_x);
  __syncthreads();  // B0

  // transposed projections: kT[e][t] = phi(sum_d WkT[e][d] x[t][d]); vT[d][t]
  short8 awk[2], awv[2];
#pragma unroll
  for (int kk = 0; kk < 2; ++kk) {
    awk[kk] = ld8(wkT + (w * 16 + lr) * 64 + kk * 32 + lq * 8);
    awv[kk] = ld8(wvT + (w * 16 + lr) * 64 + kk * 32 + lq * 8);
  }
  f32x4 ak[4] = {zero4, zero4, zero4, zero4};
  f32x4 av[4] = {zero4, zero4, zero4, zero4};
#pragma unroll
  for (int c = 0; c < 4; ++c) {
#pragma unroll
    for (int kk = 0; kk < 2; ++kk) {
      short8 bx = ld8(&s_x[(c * 16 + lr) * LP + kk * 32 + lq * 8]);
      ak[c] = MFMA_B16(awk[kk], bx, ak[c]);
      av[c] = MFMA_B16(awv[kk], bx, av[c]);
    }
  }
#pragma unroll
  for (int c = 0; c < 4; ++c) {
#pragma unroll
    for (int j = 0; j < 4; ++j) {
      int r = w * 16 + lq * 4 + j;
      s_kT[r * LP + c * 16 + lr] = f2bf(phi_elu1(ak[c][j]));
      s_vT[r * LP + c * 16 + lr] = f2bf(av[c][j]);
    }
  }
  __syncthreads();  // B1

  // kv^T[d][e] = sum_t vT[d][t] k[t][e]   (A = vT rows d, B = kT rows e)
  short8 avt[2];
#pragma unroll
  for (int kk = 0; kk < 2; ++kk)
    avt[kk] = ld8(&s_vT[(w * 16 + lr) * LP + kk * 32 + lq * 8]);
  f32x4 sacc[4] = {zero4, zero4, zero4, zero4};
#pragma unroll
  for (int c = 0; c < 4; ++c)
#pragma unroll
    for (int kk = 0; kk < 2; ++kk)
      sacc[c] = MFMA_B16(avt[kk], ld8(&s_kT[(c * 16 + lr) * LP + kk * 32 + lq * 8]), sacc[c]);

  unsigned short* dst = kvc + ((size_t)bh * NCH + ch) * 4096;
#pragma unroll
  for (int c = 0; c < 4; ++c)
#pragma unroll
    for (int j = 0; j < 4; ++j)
      dst[(w * 16 + lq * 4 + j) * 64 + c * 16 + lr] = f2bf(sacc[c][j]);
}

// ---------------- pass2: in-place exclusive prefix over chunk KVs (per bh) ----------------
// kvc[bh][ch][.] <- sum_{c<ch} kvc[bh][c][.]   (fp32 accumulate, bf16 storage)
__global__ __launch_bounds__(256) void pass2_prefix(unsigned short* __restrict__ kvc) {
  const int bh = blockIdx.x, tile = blockIdx.y;
  const int base = tile * 2048 + threadIdx.x * 8;
  unsigned short* p = kvc + (size_t)bh * NCH * 4096 + base;
  float acc[8] = {0.f, 0.f, 0.f, 0.f, 0.f, 0.f, 0.f, 0.f};
  for (int ch = 0; ch < NCH; ++ch) {
    short8 v = ld8(p + (size_t)ch * 4096);
    short8 e;
#pragma unroll
    for (int j = 0; j < 8; ++j) e[j] = (short)f2bf(acc[j]);
    st8(p + (size_t)ch * 4096, e);   // exclusive: value BEFORE adding this chunk
#pragma unroll
    for (int j = 0; j < 8; ++j) acc[j] += bf2f((unsigned short)v[j]);
  }
}

// ---------------- pass3: per-chunk output (fully parallel) ----------------
__global__ __launch_bounds__(256, 3) void pass3_out(
    const float* __restrict__ x, const unsigned short* __restrict__ wT,
    const unsigned short* __restrict__ STp, float* __restrict__ out) {
  __shared__ unsigned short s_x [64 * LP];  // x chunk, later o
  __shared__ unsigned short s_q [64 * LP];  // q[t][e]
  __shared__ unsigned short s_k [64 * LP];  // k[t][e]
  __shared__ unsigned short s_vT[64 * LP];  // v^T[d][t]
  __shared__ unsigned short s_at[64 * LP];  // masked attn[t][t']

  const int tid = threadIdx.x;
  const int w = tid >> 6, lane = tid & 63, lr = lane & 15, lq = lane >> 4;
  const int bh = blockIdx.x, ci = blockIdx.y;
  const int b = bh >> 4, h = bh & 15;
  const float* xbase = x + ((size_t)b * Tc + (size_t)ci * CHc) * Ec + h * Dc;
  float* obase = out + ((size_t)b * Tc + (size_t)ci * CHc) * Ec + h * Dc;
  const unsigned short* wqT = wT;
  const unsigned short* wkT = wT + 4096;
  const unsigned short* wvT = wT + 2 * 4096;
  const unsigned short* woT = wT + 3 * 4096;
  const unsigned short* Sb = STp + ((size_t)bh * NCH + ci) * 4096;  // ST[d][e] exclusive prefix
  const int sr = tid >> 2, sc = tid & 3;
  const int arow = (w * 16 + lr) * LP;
  const f32x4 zero4 = {0.f, 0.f, 0.f, 0.f};

  stage_x(xbase, sr, sc, s_x);
  __syncthreads();  // B0

  // ---- stage A: q = phi(x Wq), k = phi(x Wk) row-major; vT[d][t] transposed ----
  short8 awv[2];
#pragma unroll
  for (int kk = 0; kk < 2; ++kk)
    awv[kk] = ld8(wvT + (w * 16 + lr) * 64 + kk * 32 + lq * 8);
  short8 ax[2];
  ax[0] = ld8(&s_x[arow + 0 + lq * 8]);
  ax[1] = ld8(&s_x[arow + 32 + lq * 8]);
  f32x4 aq[4]  = {zero4, zero4, zero4, zero4};
  f32x4 ack[4] = {zero4, zero4, zero4, zero4};
  f32x4 acv[4] = {zero4, zero4, zero4, zero4};
#pragma unroll
  for (int c = 0; c < 4; ++c) {
    const int br = c * 16 + lr;
#pragma unroll
    for (int kk = 0; kk < 2; ++kk) {
      aq[c]  = MFMA_B16(ax[kk],  ld8(wqT + br * 64 + kk * 32 + lq * 8), aq[c]);
      ack[c] = MFMA_B16(ax[kk],  ld8(wkT + br * 64 + kk * 32 + lq * 8), ack[c]);
      acv[c] = MFMA_B16(awv[kk], ld8(&s_x[br * LP + kk * 32 + lq * 8]), acv[c]);
    }
  }
#pragma unroll
  for (int c = 0; c < 4; ++c) {
#pragma unroll
    for (int j = 0; j < 4; ++j) {
      int r = w * 16 + lq * 4 + j;
      s_q [r * LP + c * 16 + lr] = f2bf(phi_elu1(aq[c][j]));
      s_k [r * LP + c * 16 + lr] = f2bf(phi_elu1(ack[c][j]));
      s_vT[r * LP + c * 16 + lr] = f2bf(acv[c][j]);
    }
  }
  __syncthreads();  // B1

  // ---- stage B: attn = mask(q k^T); o_inter = q @ S (S from global, B-frags) ----
  short8 a_q[2];
#pragma unroll
  for (int kk = 0; kk < 2; ++kk)
    a_q[kk] = ld8(&s_q[arow + kk * 32 + lq * 8]);
  f32x4 aat[4] = {zero4, zero4, zero4, zero4};
  f32x4 ao[4]  = {zero4, zero4, zero4, zero4};
#pragma unroll
  for (int c = 0; c < 4; ++c) {
    const int br = c * 16 + lr;
#pragma unroll
    for (int kk = 0; kk < 2; ++kk) {
      aat[c] = MFMA_B16(a_q[kk], ld8(&s_k[br * LP + kk * 32 + lq * 8]), aat[c]);
      ao[c]  = MFMA_B16(a_q[kk], ld8(Sb + br * 64 + kk * 32 + lq * 8), ao[c]);
    }
  }
#pragma unroll
  for (int c = 0; c < 4; ++c) {
#pragma unroll
    for (int j = 0; j < 4; ++j) {
      int t = w * 16 + lq * 4 + j, tp = c * 16 + lr;
      s_at[t * LP + tp] = f2bf((tp <= t) ? aat[c][j] : 0.f);  // causal tril incl diag
    }
  }
  __syncthreads();  // B2

  // ---- stage C: o += attn @ v; write o into s_x (free since stage A) ----
  short8 a_at[2];
#pragma unroll
  for (int kk = 0; kk < 2; ++kk)
    a_at[kk] = ld8(&s_at[arow + kk * 32 + lq * 8]);
#pragma unroll
  for (int c = 0; c < 4; ++c)
#pragma unroll
    for (int kk = 0; kk < 2; ++kk)
      ao[c] = MFMA_B16(a_at[kk], ld8(&s_vT[(c * 16 + lr) * LP + kk * 32 + lq * 8]), ao[c]);
#pragma unroll
  for (int c = 0; c < 4; ++c)
#pragma unroll
    for (int j = 0; j < 4; ++j)
      s_x[(w * 16 + lq * 4 + j) * LP + c * 16 + lr] = f2bf(ao[c][j]);
  __syncthreads();  // B3

  // ---- stage D: out = o @ Wo -> global fp32 ----
  short8 a_o[2];
#pragma unroll
  for (int kk = 0; kk < 2; ++kk)
    a_o[kk] = ld8(&s_x[arow + kk * 32 + lq * 8]);
  f32x4 aou[4] = {zero4, zero4, zero4, zero4};
#pragma unroll
  for (int c = 0; c < 4; ++c)
#pragma unroll
    for (int kk = 0; kk < 2; ++kk)
      aou[c] = MFMA_B16(a_o[kk], ld8(woT + (c * 16 + lr) * 64 + kk * 32 + lq * 8), aou[c]);
#pragma unroll
  for (int c = 0; c < 4; ++c)
#pragma unroll
    for (int j = 0; j < 4; ++j)
      obase[(size_t)(w * 16 + lq * 4 + j) * Ec + c * 16 + lr] = aou[c][j];
}

extern "C" void kernel_launch(void* const* d_in, const int* in_sizes, int n_in,
                              void* d_out, int out_size, void* d_ws, size_t ws_size,
                              hipStream_t stream) {
  const float* x  = (const float*)d_in[0];
  const float* Wq = (const float*)d_in[1];
  const float* Wk = (const float*)d_in[2];
  const float* Wv = (const float*)d_in[3];
  const float* Wo = (const float*)d_in[4];
  float* out = (float*)d_out;

  unsigned short* wT  = (unsigned short*)d_ws;             // 4 x [64][64] bf16 = 32 KB
  unsigned short* kvc = (unsigned short*)((char*)d_ws + 32768);  // [64][64][64][64] bf16 = 32 MB

  prep_weights<<<dim3(64), dim3(256), 0, stream>>>(Wq, Wk, Wv, Wo, wT);
  pass1_kv<<<dim3(64, NCH), dim3(256), 0, stream>>>(x, wT, kvc);
  pass2_prefix<<<dim3(64, 2), dim3(256), 0, stream>>>(kvc);      // kvc -> exclusive prefix (in place)
  pass3_out<<<dim3(64, NCH), dim3(256), 0, stream>>>(x, wT, kvc, out);
}

// Round 3
// 74.087 us; speedup vs baseline: 1.6669x; 1.6669x over previous
//
#include <hip/hip_runtime.h>
#include <cstdint>
#include <cstddef>

// Problem constants (fixed by the reference)
constexpr int Bc = 4, Tc = 4096, Ec = 1024, Hc = 16, Dc = 64, CHc = 64;
constexpr int NSEG = 16;              // parallel segments per sequence
constexpr int SEGT = Tc / NSEG;       // 256 tokens per segment
constexpr int NCHUNK = SEGT / CHc;    // 4 chunks per segment (serial, S in regs)
constexpr int LP = 72;                // padded LDS row stride in bf16 elems (144B)

typedef __attribute__((ext_vector_type(8))) short short8;   // 8 bf16 MFMA A/B frag
typedef __attribute__((ext_vector_type(4))) short short4v;  // 4 bf16 (8B store)
typedef __attribute__((ext_vector_type(4))) float f32x4;    // MFMA C/D frag

__device__ __forceinline__ unsigned short f2bf(float f) {
  union { float f; unsigned int u; } v; v.f = f;
  return (unsigned short)((v.u + 0x7FFFu + ((v.u >> 16) & 1u)) >> 16);  // RNE
}
__device__ __forceinline__ float bf2f(unsigned short u) {
  union { unsigned int u; float f; } v; v.u = ((unsigned int)u) << 16;
  return v.f;
}
__device__ __forceinline__ float phi_elu1(float x) {   // elu(x)+1
  return x > 0.f ? x + 1.f : __expf(x);
}
__device__ __forceinline__ short8 ld8(const unsigned short* p) {
  return *reinterpret_cast<const short8*>(p);
}
__device__ __forceinline__ void st8(unsigned short* p, short8 v) {
  *reinterpret_cast<short8*>(p) = v;
}

#define MFMA_B16(a, b, c) __builtin_amdgcn_mfma_f32_16x16x32_bf16((a), (b), (c), 0, 0, 0)

// Convert 4 float4 (one x row-slice) to 16 bf16 and store to LDS (LP stride).
__device__ __forceinline__ void cvt_store16(unsigned short* dst, float4 f0, float4 f1,
                                            float4 f2, float4 f3) {
  union { unsigned short us[16]; short8 v[2]; } pk;
  pk.us[0] = f2bf(f0.x);  pk.us[1] = f2bf(f0.y);  pk.us[2] = f2bf(f0.z);  pk.us[3] = f2bf(f0.w);
  pk.us[4] = f2bf(f1.x);  pk.us[5] = f2bf(f1.y);  pk.us[6] = f2bf(f1.z);  pk.us[7] = f2bf(f1.w);
  pk.us[8] = f2bf(f2.x);  pk.us[9] = f2bf(f2.y);  pk.us[10] = f2bf(f2.z); pk.us[11] = f2bf(f2.w);
  pk.us[12] = f2bf(f3.x); pk.us[13] = f2bf(f3.y); pk.us[14] = f2bf(f3.z); pk.us[15] = f2bf(f3.w);
  st8(dst, pk.v[0]); st8(dst + 8, pk.v[1]);
}

// ---------------- pass0: W[d][e] fp32 -> WT[e][d] bf16 (q,k,v,o) ----------------
__global__ void prep_weights(const float* __restrict__ Wq, const float* __restrict__ Wk,
                             const float* __restrict__ Wv, const float* __restrict__ Wo,
                             unsigned short* __restrict__ wT) {
  int tid = blockIdx.x * blockDim.x + threadIdx.x;
  if (tid >= 4 * Dc * Dc) return;
  int m = tid >> 12, i = tid & 4095, d = i >> 6, e = i & 63;
  const float* W = (m == 0) ? Wq : (m == 1) ? Wk : (m == 2) ? Wv : Wo;
  wT[m * 4096 + e * 64 + d] = f2bf(W[d * 64 + e]);
}

// ---------------- pass1: per-SEGMENT KV = sum_t phi(k)^T v  -> fp32 ws ----------------
// grid (64 bh, 16 seg); 4 chunks serial; x double-buffered; frags preloaded.
__global__ __launch_bounds__(256, 3) void pass1_kvseg(
    const float* __restrict__ x, const unsigned short* __restrict__ wT,
    float* __restrict__ kvseg) {
  __shared__ unsigned short s_x[2 * 64 * LP];
  __shared__ unsigned short s_kT[64 * LP];
  __shared__ unsigned short s_vT[64 * LP];

  const int tid = threadIdx.x;
  const int w = tid >> 6, lane = tid & 63, lr = lane & 15, lq = lane >> 4;
  const int bh = blockIdx.x, sg = blockIdx.y;
  const int b = bh >> 4, h = bh & 15;
  const float* xbase = x + ((size_t)b * Tc + (size_t)sg * SEGT) * Ec + h * Dc;
  const unsigned short* wkT = wT + 4096;
  const unsigned short* wvT = wT + 2 * 4096;
  const int sr = tid >> 2, sc = tid & 3;
  const f32x4 zero4 = {0.f, 0.f, 0.f, 0.f};

  // preload loop-invariant A-frags (WkT/WvT rows w*16+lr)
  short8 awk[2], awv[2];
#pragma unroll
  for (int kk = 0; kk < 2; ++kk) {
    awk[kk] = ld8(wkT + (w * 16 + lr) * 64 + kk * 32 + lq * 8);
    awv[kk] = ld8(wvT + (w * 16 + lr) * 64 + kk * 32 + lq * 8);
  }

  {  // stage chunk 0
    const float4* xf = reinterpret_cast<const float4*>(xbase + (size_t)sr * Ec + sc * 16);
    cvt_store16(&s_x[sr * LP + sc * 16], xf[0], xf[1], xf[2], xf[3]);
  }
  __syncthreads();  // B0

  f32x4 sacc[4] = {zero4, zero4, zero4, zero4};

#pragma unroll
  for (int ci = 0; ci < NCHUNK; ++ci) {
    unsigned short* sxc = &s_x[(ci & 1) * 64 * LP];
    unsigned short* sxn = &s_x[(1 - (ci & 1)) * 64 * LP];

    // prefetch next chunk's x (issue early; consumed at chunk end)
    float4 pf0, pf1, pf2, pf3;
    if (ci < NCHUNK - 1) {
      const float4* xf = reinterpret_cast<const float4*>(
          xbase + (size_t)((ci + 1) * CHc + sr) * Ec + sc * 16);
      pf0 = xf[0]; pf1 = xf[1]; pf2 = xf[2]; pf3 = xf[3];
    }

    // transposed projections: kT[e][t] = phi(.), vT[d][t]
    f32x4 ak[4] = {zero4, zero4, zero4, zero4};
    f32x4 av[4] = {zero4, zero4, zero4, zero4};
#pragma unroll
    for (int c = 0; c < 4; ++c) {
#pragma unroll
      for (int kk = 0; kk < 2; ++kk) {
        short8 bx = ld8(&sxc[(c * 16 + lr) * LP + kk * 32 + lq * 8]);
        ak[c] = MFMA_B16(awk[kk], bx, ak[c]);
        av[c] = MFMA_B16(awv[kk], bx, av[c]);
      }
    }
#pragma unroll
    for (int c = 0; c < 4; ++c) {
#pragma unroll
      for (int j = 0; j < 4; ++j) {
        int r = w * 16 + lq * 4 + j;
        s_kT[r * LP + c * 16 + lr] = f2bf(phi_elu1(ak[c][j]));
        s_vT[r * LP + c * 16 + lr] = f2bf(av[c][j]);
      }
    }
    __syncthreads();  // B1

    // state update: ST[d][e] += sum_t vT[d][t] k[t][e]
    short8 avt[2];
#pragma unroll
    for (int kk = 0; kk < 2; ++kk)
      avt[kk] = ld8(&s_vT[(w * 16 + lr) * LP + kk * 32 + lq * 8]);
#pragma unroll
    for (int c = 0; c < 4; ++c)
#pragma unroll
      for (int kk = 0; kk < 2; ++kk)
        sacc[c] = MFMA_B16(avt[kk], ld8(&s_kT[(c * 16 + lr) * LP + kk * 32 + lq * 8]), sacc[c]);

    if (ci < NCHUNK - 1)
      cvt_store16(&sxn[sr * LP + sc * 16], pf0, pf1, pf2, pf3);
    __syncthreads();  // B2 (kT/vT reads done; next x buffer ready)
  }

  float* dst = kvseg + ((size_t)(bh * NSEG + sg)) * 4096;
#pragma unroll
  for (int c = 0; c < 4; ++c)
#pragma unroll
    for (int j = 0; j < 4; ++j)
      dst[(w * 16 + lq * 4 + j) * 64 + c * 16 + lr] = sacc[c][j];
}

// ---------------- pass2: exclusive prefix over 16 segment KVs (per bh elem) ----------------
// sprefix[bh][sg][.] = sum_{s<sg} kvseg[bh][s][.]   (fp32 in, bf16 out)
__global__ __launch_bounds__(256) void pass2_prefix(const float* __restrict__ kvseg,
                                                    unsigned short* __restrict__ sprefix) {
  const int bh = blockIdx.x, tile = blockIdx.y;
  const int e = tile * 1024 + threadIdx.x * 4;
  const float* src = kvseg + (size_t)bh * NSEG * 4096 + e;
  unsigned short* dst = sprefix + (size_t)bh * NSEG * 4096 + e;
  float4 vals[NSEG];
#pragma unroll
  for (int s = 0; s < NSEG; ++s)
    vals[s] = *reinterpret_cast<const float4*>(src + (size_t)s * 4096);
  float a0 = 0.f, a1 = 0.f, a2 = 0.f, a3 = 0.f;
#pragma unroll
  for (int s = 0; s < NSEG; ++s) {
    short4v sv;
    sv[0] = (short)f2bf(a0); sv[1] = (short)f2bf(a1);
    sv[2] = (short)f2bf(a2); sv[3] = (short)f2bf(a3);
    *reinterpret_cast<short4v*>(dst + (size_t)s * 4096) = sv;  // exclusive
    a0 += vals[s].x; a1 += vals[s].y; a2 += vals[s].z; a3 += vals[s].w;
  }
}

// ---------------- pass3: main per-segment recurrence (4 chunks serial) ----------------
__global__ __launch_bounds__(256, 2) void pass3_main(
    const float* __restrict__ x, const unsigned short* __restrict__ wT,
    const unsigned short* __restrict__ sprefix, float* __restrict__ out) {
  __shared__ unsigned short s_x[2 * 64 * LP];  // x chunks (dbuf); cur half doubles as 'attn'
  __shared__ unsigned short s_q [64 * LP];     // q, later o
  __shared__ unsigned short s_k [64 * LP];     // k row-major
  __shared__ unsigned short s_kT[64 * LP];     // k^T
  __shared__ unsigned short s_vT[64 * LP];     // v^T
  __shared__ unsigned short s_Sb[64 * LP];     // ST[d][e] bf16 (state snapshot)

  const int tid = threadIdx.x;
  const int w = tid >> 6, lane = tid & 63, lr = lane & 15, lq = lane >> 4;
  const int bh = blockIdx.x, sg = blockIdx.y;
  const int b = bh >> 4, h = bh & 15;
  const float* xbase = x + ((size_t)b * Tc + (size_t)sg * SEGT) * Ec + h * Dc;
  float* obase = out + ((size_t)b * Tc + (size_t)sg * SEGT) * Ec + h * Dc;
  const unsigned short* wqT = wT;
  const unsigned short* wkT = wT + 4096;
  const unsigned short* wvT = wT + 2 * 4096;
  const unsigned short* woT = wT + 3 * 4096;
  const unsigned short* Sg = sprefix + ((size_t)(bh * NSEG + sg)) * 4096;
  const int sr = tid >> 2, sc = tid & 3;
  const int arow = (w * 16 + lr) * LP;
  const f32x4 zero4 = {0.f, 0.f, 0.f, 0.f};

  // ---- preload ALL weight fragments into registers (one waitcnt for 26 loads) ----
  short8 bwq[4][2], bwk[4][2], bwo[4][2], awv[2];
#pragma unroll
  for (int c = 0; c < 4; ++c) {
#pragma unroll
    for (int kk = 0; kk < 2; ++kk) {
      bwq[c][kk] = ld8(wqT + (c * 16 + lr) * 64 + kk * 32 + lq * 8);
      bwk[c][kk] = ld8(wkT + (c * 16 + lr) * 64 + kk * 32 + lq * 8);
      bwo[c][kk] = ld8(woT + (c * 16 + lr) * 64 + kk * 32 + lq * 8);
    }
  }
#pragma unroll
  for (int kk = 0; kk < 2; ++kk)
    awv[kk] = ld8(wvT + (w * 16 + lr) * 64 + kk * 32 + lq * 8);

  {  // stage chunk 0 x and the segment's S-prefix into LDS
    const float4* xf = reinterpret_cast<const float4*>(xbase + (size_t)sr * Ec + sc * 16);
    cvt_store16(&s_x[sr * LP + sc * 16], xf[0], xf[1], xf[2], xf[3]);
    const unsigned short* sp = Sg + sr * 64 + (tid & 3) * 16;
    st8(&s_Sb[sr * LP + (tid & 3) * 16], ld8(sp));
    st8(&s_Sb[sr * LP + (tid & 3) * 16 + 8], ld8(sp + 8));
  }
  __syncthreads();  // B0

  // running state in fp32 regs, seeded from the bf16 prefix
  f32x4 sacc[4];
#pragma unroll
  for (int c = 0; c < 4; ++c)
#pragma unroll
    for (int j = 0; j < 4; ++j)
      sacc[c][j] = bf2f(s_Sb[(w * 16 + lq * 4 + j) * LP + c * 16 + lr]);

#pragma unroll
  for (int ci = 0; ci < NCHUNK; ++ci) {
    unsigned short* sxc = &s_x[(ci & 1) * 64 * LP];   // current x, becomes attn buffer
    unsigned short* sxn = &s_x[(1 - (ci & 1)) * 64 * LP];

    // prefetch next chunk's x (latency spans the whole chunk)
    float4 pf0, pf1, pf2, pf3;
    if (ci < NCHUNK - 1) {
      const float4* xf = reinterpret_cast<const float4*>(
          xbase + (size_t)((ci + 1) * CHc + sr) * Ec + sc * 16);
      pf0 = xf[0]; pf1 = xf[1]; pf2 = xf[2]; pf3 = xf[3];
    }

    // ---- stage A: q = phi(x Wq), k = phi(x Wk) (+kT), vT ----
    short8 ax[2];
    ax[0] = ld8(&sxc[arow + 0 + lq * 8]);
    ax[1] = ld8(&sxc[arow + 32 + lq * 8]);
    f32x4 aq[4]  = {zero4, zero4, zero4, zero4};
    f32x4 ack[4] = {zero4, zero4, zero4, zero4};
    f32x4 acv[4] = {zero4, zero4, zero4, zero4};
#pragma unroll
    for (int c = 0; c < 4; ++c) {
#pragma unroll
      for (int kk = 0; kk < 2; ++kk) {
        aq[c]  = MFMA_B16(ax[kk],  bwq[c][kk], aq[c]);
        ack[c] = MFMA_B16(ax[kk],  bwk[c][kk], ack[c]);
        acv[c] = MFMA_B16(awv[kk], ld8(&sxc[(c * 16 + lr) * LP + kk * 32 + lq * 8]), acv[c]);
      }
    }
#pragma unroll
    for (int c = 0; c < 4; ++c) {
#pragma unroll
      for (int j = 0; j < 4; ++j) {
        int r = w * 16 + lq * 4 + j;
        float kv2 = phi_elu1(ack[c][j]);
        s_q [r * LP + c * 16 + lr] = f2bf(phi_elu1(aq[c][j]));
        s_k [r * LP + c * 16 + lr] = f2bf(kv2);
        s_kT[(c * 16 + lr) * LP + r] = f2bf(kv2);
        s_vT[r * LP + c * 16 + lr] = f2bf(acv[c][j]);
      }
    }
    __syncthreads();  // B1

    // ---- stage B: attn = mask(q k^T); o_inter = q @ S; S += v^T k ----
    short8 a_q[2], a_v[2];
#pragma unroll
    for (int kk = 0; kk < 2; ++kk) {
      a_q[kk] = ld8(&s_q[arow + kk * 32 + lq * 8]);
      a_v[kk] = ld8(&s_vT[arow + kk * 32 + lq * 8]);
    }
    f32x4 aat[4] = {zero4, zero4, zero4, zero4};
    f32x4 ao[4]  = {zero4, zero4, zero4, zero4};
#pragma unroll
    for (int c = 0; c < 4; ++c) {
      const int br = (c * 16 + lr) * LP;
#pragma unroll
      for (int kk = 0; kk < 2; ++kk) {
        aat[c]  = MFMA_B16(a_q[kk], ld8(&s_k[br + kk * 32 + lq * 8]), aat[c]);
        ao[c]   = MFMA_B16(a_q[kk], ld8(&s_Sb[br + kk * 32 + lq * 8]), ao[c]);
        sacc[c] = MFMA_B16(a_v[kk], ld8(&s_kT[br + kk * 32 + lq * 8]), sacc[c]);
      }
    }
#pragma unroll
    for (int c = 0; c < 4; ++c) {
#pragma unroll
      for (int j = 0; j < 4; ++j) {
        int t = w * 16 + lq * 4 + j, tp = c * 16 + lr;
        sxc[t * LP + tp] = f2bf((tp <= t) ? aat[c][j] : 0.f);  // attn into x[cur] buffer
      }
    }
    __syncthreads();  // B2

    // ---- stage C: o += attn @ v -> s_q; refresh S snapshot for next chunk ----
    short8 a_at[2];
#pragma unroll
    for (int kk = 0; kk < 2; ++kk)
      a_at[kk] = ld8(&sxc[arow + kk * 32 + lq * 8]);
#pragma unroll
    for (int c = 0; c < 4; ++c)
#pragma unroll
      for (int kk = 0; kk < 2; ++kk)
        ao[c] = MFMA_B16(a_at[kk], ld8(&s_vT[(c * 16 + lr) * LP + kk * 32 + lq * 8]), ao[c]);
#pragma unroll
    for (int c = 0; c < 4; ++c) {
#pragma unroll
      for (int j = 0; j < 4; ++j) {
        int r = w * 16 + lq * 4 + j;
        s_q[r * LP + c * 16 + lr] = f2bf(ao[c][j]);
        if (ci < NCHUNK - 1)
          s_Sb[r * LP + c * 16 + lr] = f2bf(sacc[c][j]);
      }
    }
    __syncthreads();  // B3

    // ---- stage D: out = o @ Wo -> global; write prefetched x ----
    short8 a_o[2];
#pragma unroll
    for (int kk = 0; kk < 2; ++kk)
      a_o[kk] = ld8(&s_q[arow + kk * 32 + lq * 8]);
    f32x4 aou[4] = {zero4, zero4, zero4, zero4};
#pragma unroll
    for (int c = 0; c < 4; ++c)
#pragma unroll
      for (int kk = 0; kk < 2; ++kk)
        aou[c] = MFMA_B16(a_o[kk], bwo[c][kk], aou[c]);
    float* orow = obase + (size_t)(ci * CHc) * Ec;
#pragma unroll
    for (int c = 0; c < 4; ++c)
#pragma unroll
      for (int j = 0; j < 4; ++j)
        orow[(size_t)(w * 16 + lq * 4 + j) * Ec + c * 16 + lr] = aou[c][j];

    if (ci < NCHUNK - 1)
      cvt_store16(&sxn[sr * LP + sc * 16], pf0, pf1, pf2, pf3);
    __syncthreads();  // B4
  }
}

extern "C" void kernel_launch(void* const* d_in, const int* in_sizes, int n_in,
                              void* d_out, int out_size, void* d_ws, size_t ws_size,
                              hipStream_t stream) {
  const float* x  = (const float*)d_in[0];
  const float* Wq = (const float*)d_in[1];
  const float* Wk = (const float*)d_in[2];
  const float* Wv = (const float*)d_in[3];
  const float* Wo = (const float*)d_in[4];
  float* out = (float*)d_out;

  unsigned short* wT = (unsigned short*)d_ws;                        // 32 KB
  float* kvseg = (float*)((char*)d_ws + 32768);                     // 16 MB fp32
  unsigned short* sprefix = (unsigned short*)((char*)d_ws + 32768 + (size_t)16 * 1024 * 1024);  // 8 MB bf16

  prep_weights<<<dim3(64), dim3(256), 0, stream>>>(Wq, Wk, Wv, Wo, wT);
  pass1_kvseg<<<dim3(64, NSEG), dim3(256), 0, stream>>>(x, wT, kvseg);
  pass2_prefix<<<dim3(64, 4), dim3(256), 0, stream>>>(kvseg, sprefix);
  pass3_main<<<dim3(64, NSEG), dim3(256), 0, stream>>>(x, wT, sprefix, out);
}